// Round 1
// baseline (225.335 us; speedup 1.0000x reference)
//
#include <hip/hip_runtime.h>
#include <math.h>

#define NQ   10
#define DIM  1024      // 1 << NQ
#define NB   10
#define NPTS 128
#define SQRT1_2F 0.70710678118654752440f

// ---------------------------------------------------------------------------
// Kernel A: simulate psi(x) = F(x, params)|0> for each data point.
// One block per point; full 1024-amplitude state lives in LDS (split re/im).
// ---------------------------------------------------------------------------
__global__ __launch_bounds__(256)
void states_kernel(const float* __restrict__ data,     // [NPTS, NB*NQ]
                   const float* __restrict__ params,   // [NB, 2, NQ]
                   float2* __restrict__ psi)           // [NPTS, DIM]
{
    __shared__ float sRe[DIM];
    __shared__ float sIm[DIM];
    __shared__ float sAng[NQ];
    __shared__ float sC[NQ];
    __shared__ float sS[NQ];

    const int tid = threadIdx.x;
    const int pt  = blockIdx.x;

    // |0...0>
    for (int d = tid; d < DIM; d += 256) { sRe[d] = 0.f; sIm[d] = 0.f; }
    if (tid == 0) sRe[0] = 1.f;
    __syncthreads();

    for (int j = 0; j < NB; ++j) {
        // ---- H layer (10 butterflies) ----
        for (int q = 0; q < NQ; ++q) {
            const int pos  = NQ - 1 - q;
            const int bit  = 1 << pos;
            const int mask = bit - 1;
            #pragma unroll
            for (int p = 0; p < 2; ++p) {
                const int pr = tid + p * 256;              // pair index 0..511
                const int i0 = ((pr & ~mask) << 1) | (pr & mask);
                const int i1 = i0 | bit;
                const float a0r = sRe[i0], a0i = sIm[i0];
                const float a1r = sRe[i1], a1i = sIm[i1];
                sRe[i0] = (a0r + a1r) * SQRT1_2F;
                sIm[i0] = (a0i + a1i) * SQRT1_2F;
                sRe[i1] = (a0r - a1r) * SQRT1_2F;
                sIm[i1] = (a0i - a1i) * SQRT1_2F;
            }
            __syncthreads();
        }

        // ---- RZ diagonal with data block j ----
        if (tid < NQ) sAng[tid] = data[pt * (NB * NQ) + j * NQ + tid];
        __syncthreads();
        for (int d = tid; d < DIM; d += 256) {
            float ph = 0.f;
            #pragma unroll
            for (int q = 0; q < NQ; ++q) {
                const float b = (float)((d >> (NQ - 1 - q)) & 1);
                ph += (b - 0.5f) * sAng[q];
            }
            float s, c;
            sincosf(ph, &s, &c);
            const float ar = sRe[d], ai = sIm[d];
            sRe[d] = ar * c - ai * s;
            sIm[d] = ar * s + ai * c;
        }
        __syncthreads();

        // ---- RY layer with params[j,0,:] ----
        if (tid < NQ) {
            float s, c;
            sincosf(params[j * 2 * NQ + tid] * 0.5f, &s, &c);
            sC[tid] = c;
            sS[tid] = s;
        }
        __syncthreads();
        for (int q = 0; q < NQ; ++q) {
            const int pos  = NQ - 1 - q;
            const int bit  = 1 << pos;
            const int mask = bit - 1;
            const float c = sC[q], s = sS[q];
            #pragma unroll
            for (int p = 0; p < 2; ++p) {
                const int pr = tid + p * 256;
                const int i0 = ((pr & ~mask) << 1) | (pr & mask);
                const int i1 = i0 | bit;
                const float a0r = sRe[i0], a0i = sIm[i0];
                const float a1r = sRe[i1], a1i = sIm[i1];
                sRe[i0] = c * a0r - s * a1r;
                sIm[i0] = c * a0i - s * a1i;
                sRe[i1] = s * a0r + c * a1r;
                sIm[i1] = s * a0i + c * a1i;
            }
            __syncthreads();
        }

        // ---- CRZ ring diagonal with params[j,1,:] ----
        if (tid < NQ) sAng[tid] = params[j * 2 * NQ + NQ + tid];
        __syncthreads();
        for (int d = tid; d < DIM; d += 256) {
            float ph = 0.f;
            #pragma unroll
            for (int q = 0; q < NQ; ++q) {
                const float bq  = (float)((d >> (NQ - 1 - q)) & 1);
                const float bq1 = (float)((d >> (NQ - 1 - ((q + 1) % NQ))) & 1);
                ph += sAng[q] * bq * (bq1 - 0.5f);
            }
            float s, c;
            sincosf(ph, &s, &c);
            const float ar = sRe[d], ai = sIm[d];
            sRe[d] = ar * c - ai * s;
            sIm[d] = ar * s + ai * c;
        }
        __syncthreads();
    }

    for (int d = tid; d < DIM; d += 256)
        psi[pt * DIM + d] = make_float2(sRe[d], sIm[d]);
}

// ---------------------------------------------------------------------------
// Kernel B: Gram + reduction. One wavefront per (i,j) pair.
// K[i,j] = |<psi_i|psi_j>|^2 ; accumulate polarity and sum(K^2) in double.
// ---------------------------------------------------------------------------
__global__ __launch_bounds__(256)
void gram_kernel(const float2* __restrict__ psi,
                 const float* __restrict__ labels,
                 double* __restrict__ acc)            // acc[0]=polarity, acc[1]=sumK2
{
    const int wave = threadIdx.x >> 6;                // 0..3
    const int lane = threadIdx.x & 63;
    const int pair = blockIdx.x * 4 + wave;           // 0..16383
    const int i = pair >> 7;
    const int jj = pair & 127;

    const float2* __restrict__ pi = psi + i  * DIM;
    const float2* __restrict__ pj = psi + jj * DIM;

    float gr = 0.f, gi = 0.f;
    #pragma unroll
    for (int d = lane; d < DIM; d += 64) {
        const float2 a = pi[d];
        const float2 b = pj[d];
        // conj(a)*b
        gr += a.x * b.x + a.y * b.y;
        gi += a.x * b.y - a.y * b.x;
    }
    #pragma unroll
    for (int off = 32; off > 0; off >>= 1) {
        gr += __shfl_xor(gr, off);
        gi += __shfl_xor(gi, off);
    }

    __shared__ double sPol[4];
    __shared__ double sK2[4];
    if (lane == 0) {
        const float K  = gr * gr + gi * gi;
        const float ll = labels[i] * labels[jj];
        sPol[wave] = (double)(ll * K);
        sK2[wave]  = (double)K * (double)K;
    }
    __syncthreads();
    if (threadIdx.x == 0) {
        atomicAdd(&acc[0], sPol[0] + sPol[1] + sPol[2] + sPol[3]);
        atomicAdd(&acc[1], sK2[0] + sK2[1] + sK2[2] + sK2[3]);
    }
}

__global__ void init_acc(double* acc) {
    acc[0] = 0.0;
    acc[1] = 0.0;
}

__global__ void finalize_kernel(const double* __restrict__ acc,
                                const float* __restrict__ labels,
                                float* __restrict__ out)
{
    double sumL2 = 0.0;
    for (int i = 0; i < NPTS; ++i) {
        const double l = (double)labels[i];
        sumL2 += l * l;
    }
    // norm = sqrt(sumK2 * (sumL2)^2) = sumL2 * sqrt(sumK2)
    out[0] = (float)(acc[0] / (sumL2 * sqrt(acc[1])));
}

// ---------------------------------------------------------------------------
extern "C" void kernel_launch(void* const* d_in, const int* in_sizes, int n_in,
                              void* d_out, int out_size, void* d_ws, size_t ws_size,
                              hipStream_t stream)
{
    const float* data   = (const float*)d_in[0];   // [128,100]
    const float* labels = (const float*)d_in[1];   // [128]
    const float* params = (const float*)d_in[2];   // [10,2,10]
    float* out = (float*)d_out;

    float2* psi = (float2*)d_ws;                                   // 1 MiB
    double* acc = (double*)((char*)d_ws + (size_t)NPTS * DIM * sizeof(float2));

    init_acc<<<1, 1, 0, stream>>>(acc);
    states_kernel<<<NPTS, 256, 0, stream>>>(data, params, psi);
    gram_kernel<<<(NPTS * NPTS) / 4, 256, 0, stream>>>(psi, labels, acc);
    finalize_kernel<<<1, 1, 0, stream>>>(acc, labels, out);
}

// Round 2
// 98.330 us; speedup vs baseline: 2.2916x; 2.2916x over previous
//
#include <hip/hip_runtime.h>
#include <math.h>

#define NQ   10
#define DIM  1024
#define NB   10
#define NPTS 128
#define S2   0.70710678118654752440f

// ---------------------------------------------------------------------------
// helpers
// ---------------------------------------------------------------------------
__device__ __forceinline__ void cmul_ph(float& vr, float& vi, float ph) {
    float s, c;
    __sincosf(ph, &s, &c);
    const float ar = vr, ai = vi;
    vr = ar * c - ai * s;
    vi = ar * s + ai * c;
}

#define H_PAIR(i0, i1) {                                   \
    const float ar = vr[i0], ai = vi[i0];                  \
    const float br = vr[i1], bi = vi[i1];                  \
    vr[i0] = (ar + br) * S2;  vi[i0] = (ai + bi) * S2;     \
    vr[i1] = (ar - br) * S2;  vi[i1] = (ai - bi) * S2; }

#define RY_PAIR(i0, i1, c, s) {                            \
    const float ar = vr[i0], ai = vi[i0];                  \
    const float br = vr[i1], bi = vi[i1];                  \
    vr[i0] = c * ar - s * br;  vi[i0] = c * ai - s * bi;   \
    vr[i1] = s * ar + c * br;  vi[i1] = s * ai + c * bi; }

// ---------------------------------------------------------------------------
// Kernel A: simulate psi(x) = F(x, params)|0>. One block (256 thr) per point.
// State fully in registers: 4 amps/thread.
//   canonical layout : d = w*256 + lane*4 + r   (reg bits = d-bits [1:0])
//   transposed layout: d = k*256 + lane*4 + w   (reg bits = d-bits [9:8])
// Qubit q acts on d-bit p = 9-q.
// ---------------------------------------------------------------------------
__global__ __launch_bounds__(256)
void states_kernel(const float* __restrict__ data,
                   const float* __restrict__ params,
                   float2* __restrict__ psi,
                   double* __restrict__ acc)
{
    __shared__ float sRe[DIM];
    __shared__ float sIm[DIM];

    const int tid  = threadIdx.x;
    const int w    = tid >> 6;
    const int lane = tid & 63;
    const int pt   = blockIdx.x;

    const int cbase = w * 256 + lane * 4;  // canonical amps: cbase + r
    const int tb    = lane * 4 + w;        // transposed amps: k*256 + tb

    if (pt == 0 && tid == 0) { acc[0] = 0.0; acc[1] = 0.0; }

    float vr[4], vi[4];
    vr[0] = vr[1] = vr[2] = vr[3] = 0.f;
    vi[0] = vi[1] = vi[2] = vi[3] = 0.f;
    if (tid == 0) vr[0] = 1.f;

    const float* x = data + pt * (NB * NQ);

    for (int j = 0; j < NB; ++j) {
        const float* ry  = params + j * 2 * NQ;  // RY angles
        const float* crz = ry + NQ;              // CRZ angles
        const float* xb  = x + j * NQ;           // RZ angles (data)

        // ================= H layer =================
        // canonical local: d-bits 1,0  (q = 8, 9)
        H_PAIR(0, 2) H_PAIR(1, 3)
        H_PAIR(0, 1) H_PAIR(2, 3)
        // lane bits: d-bit 2+l  (q = 7-l)
        #pragma unroll
        for (int l = 0; l < 6; ++l) {
            const float sg = ((lane >> l) & 1) ? -1.f : 1.f;
            #pragma unroll
            for (int r = 0; r < 4; ++r) {
                const float ur = __shfl_xor(vr[r], 1 << l, 64);
                const float ui = __shfl_xor(vi[r], 1 << l, 64);
                vr[r] = (ur + sg * vr[r]) * S2;
                vi[r] = (ui + sg * vi[r]) * S2;
            }
        }
        // transpose canonical -> transposed
        __syncthreads();
        *(float4*)&sRe[cbase] = make_float4(vr[0], vr[1], vr[2], vr[3]);
        *(float4*)&sIm[cbase] = make_float4(vi[0], vi[1], vi[2], vi[3]);
        __syncthreads();
        #pragma unroll
        for (int k = 0; k < 4; ++k) { vr[k] = sRe[k * 256 + tb]; vi[k] = sIm[k * 256 + tb]; }
        // transposed local: d-bits 9,8  (q = 0, 1)
        H_PAIR(0, 2) H_PAIR(1, 3)
        H_PAIR(0, 1) H_PAIR(2, 3)

        // ================= RZ diagonal (transposed) =================
        {
            const float x0 = xb[0], x1 = xb[1];
            float base_ph = -0.5f * (x0 + x1);
            #pragma unroll
            for (int q = 2; q < NQ; ++q)
                base_ph += (((tb >> (9 - q)) & 1) - 0.5f) * xb[q];
            cmul_ph(vr[0], vi[0], base_ph);
            cmul_ph(vr[1], vi[1], base_ph + x1);        // reg bit0 = d-bit8 = q1
            cmul_ph(vr[2], vi[2], base_ph + x0);        // reg bit1 = d-bit9 = q0
            cmul_ph(vr[3], vi[3], base_ph + x0 + x1);
        }

        // ================= RY layer =================
        // transposed local: q=0 (reg bit1), q=1 (reg bit0)
        {
            float c, s;
            __sincosf(ry[0] * 0.5f, &s, &c);
            RY_PAIR(0, 2, c, s) RY_PAIR(1, 3, c, s)
            __sincosf(ry[1] * 0.5f, &s, &c);
            RY_PAIR(0, 1, c, s) RY_PAIR(2, 3, c, s)
        }
        // lane bits: d-bit 2+l  (q = 7-l)
        #pragma unroll
        for (int l = 0; l < 6; ++l) {
            float c, s;
            __sincosf(ry[7 - l] * 0.5f, &s, &c);
            const float ss = ((lane >> l) & 1) ? s : -s;
            #pragma unroll
            for (int r = 0; r < 4; ++r) {
                const float ur = __shfl_xor(vr[r], 1 << l, 64);
                const float ui = __shfl_xor(vi[r], 1 << l, 64);
                vr[r] = c * vr[r] + ss * ur;
                vi[r] = c * vi[r] + ss * ui;
            }
        }
        // transpose back transposed -> canonical
        __syncthreads();
        #pragma unroll
        for (int k = 0; k < 4; ++k) { sRe[k * 256 + tb] = vr[k]; sIm[k * 256 + tb] = vi[k]; }
        __syncthreads();
        {
            const float4 fr = *(const float4*)&sRe[cbase];
            const float4 fi = *(const float4*)&sIm[cbase];
            vr[0] = fr.x; vr[1] = fr.y; vr[2] = fr.z; vr[3] = fr.w;
            vi[0] = fi.x; vi[1] = fi.y; vi[2] = fi.z; vi[3] = fi.w;
        }
        // canonical local: q=8 (reg bit1), q=9 (reg bit0)
        {
            float c, s;
            __sincosf(ry[8] * 0.5f, &s, &c);
            RY_PAIR(0, 2, c, s) RY_PAIR(1, 3, c, s)
            __sincosf(ry[9] * 0.5f, &s, &c);
            RY_PAIR(0, 1, c, s) RY_PAIR(2, 3, c, s)
        }

        // ================= CRZ ring diagonal (canonical) =================
        {
            const int hb = (w << 6) | lane;      // d-bits [9:2]
            float common = 0.f;
            #pragma unroll
            for (int q = 0; q <= 6; ++q) {       // control pos 9-q, target pos 8-q (both >=2)
                const float bq  = (float)((hb >> (7 - q)) & 1);
                const float bq1 = (float)((hb >> (6 - q)) & 1);
                common += crz[q] * bq * (bq1 - 0.5f);
            }
            const float b2 = (float)(hb & 1);          // d-bit2
            const float b9 = (float)((hb >> 7) & 1);   // d-bit9
            const float t7 = crz[7], t8 = crz[8], t9 = crz[9];
            #pragma unroll
            for (int r = 0; r < 4; ++r) {
                const float r1 = (float)((r >> 1) & 1);  // d-bit1
                const float r0 = (float)(r & 1);         // d-bit0
                const float ph = common
                               + t7 * b2 * (r1 - 0.5f)
                               + t8 * r1 * (r0 - 0.5f)
                               + t9 * r0 * (b9 - 0.5f);
                cmul_ph(vr[r], vi[r], ph);
            }
        }
    }

    // write out (canonical): 4 consecutive float2 per thread
    float2* out = psi + pt * DIM + cbase;
    *(float4*)&out[0] = make_float4(vr[0], vi[0], vr[1], vi[1]);
    *(float4*)&out[2] = make_float4(vr[2], vi[2], vr[3], vi[3]);
}

// ---------------------------------------------------------------------------
// Kernel B: tiled complex Gram. 32x32 output tile x 16 K-chunks = 256 blocks.
// Each thread: 2x2 accumulator. A:[row][k] pitch 66, B transposed:[k][col]
// pitch 34 (conflict <= 2-way, float4 LDS reads).
// ---------------------------------------------------------------------------
#define TS 32
#define KC 64
#define KSPLIT (DIM / KC)   // 16

__global__ __launch_bounds__(256)
void gram_kernel(const float2* __restrict__ psi, float2* __restrict__ Gpart)
{
    __shared__ float2 A [TS][KC + 2];   // pitch 66 float2
    __shared__ float2 Bt[KC][TS + 2];   // pitch 34 float2

    const int tid  = threadIdx.x;
    const int bx   = blockIdx.x;
    const int ks   = bx & 15;
    const int tile = bx >> 4;
    const int ti   = tile >> 2, tj = tile & 3;
    const int kbase = ks * KC;

    // stage: each thread loads 4 consecutive complex for one row of A and B
    #pragma unroll
    for (int it = 0; it < 2; ++it) {
        const int slot = it * 256 + tid;
        const int row  = slot >> 4;          // 0..31
        const int kq   = (slot & 15) << 2;   // 0,4,...,60
        const float4* sa = (const float4*)(psi + (ti * TS + row) * DIM + kbase + kq);
        const float4 a01 = sa[0], a23 = sa[1];
        *(float4*)&A[row][kq]     = a01;
        *(float4*)&A[row][kq + 2] = a23;
        const float4* sb = (const float4*)(psi + (tj * TS + row) * DIM + kbase + kq);
        const float4 b01 = sb[0], b23 = sb[1];
        Bt[kq + 0][row] = make_float2(b01.x, b01.y);
        Bt[kq + 1][row] = make_float2(b01.z, b01.w);
        Bt[kq + 2][row] = make_float2(b23.x, b23.y);
        Bt[kq + 3][row] = make_float2(b23.z, b23.w);
    }
    __syncthreads();

    const int ty = tid >> 4, tx = tid & 15;
    float g00r = 0.f, g00i = 0.f, g01r = 0.f, g01i = 0.f;
    float g10r = 0.f, g10i = 0.f, g11r = 0.f, g11i = 0.f;

    #pragma unroll 4
    for (int k = 0; k < KC; k += 2) {
        const float4 a0 = *(const float4*)&A[2 * ty    ][k];      // rows: (k),(k+1)
        const float4 a1 = *(const float4*)&A[2 * ty + 1][k];
        const float4 b0 = *(const float4*)&Bt[k    ][2 * tx];     // cols: c0,c1 at k
        const float4 b1 = *(const float4*)&Bt[k + 1][2 * tx];
        g00r += a0.x * b0.x + a0.y * b0.y;  g00i += a0.x * b0.y - a0.y * b0.x;
        g01r += a0.x * b0.z + a0.y * b0.w;  g01i += a0.x * b0.w - a0.y * b0.z;
        g10r += a1.x * b0.x + a1.y * b0.y;  g10i += a1.x * b0.y - a1.y * b0.x;
        g11r += a1.x * b0.z + a1.y * b0.w;  g11i += a1.x * b0.w - a1.y * b0.z;
        g00r += a0.z * b1.x + a0.w * b1.y;  g00i += a0.z * b1.y - a0.w * b1.x;
        g01r += a0.z * b1.z + a0.w * b1.w;  g01i += a0.z * b1.w - a0.w * b1.z;
        g10r += a1.z * b1.x + a1.w * b1.y;  g10i += a1.z * b1.y - a1.w * b1.x;
        g11r += a1.z * b1.z + a1.w * b1.w;  g11i += a1.z * b1.w - a1.w * b1.z;
    }

    float2* gp = Gpart + ks * (NPTS * NPTS);
    const int gr0 = ti * TS + 2 * ty, gc0 = tj * TS + 2 * tx;
    gp[(gr0    ) * NPTS + gc0    ] = make_float2(g00r, g00i);
    gp[(gr0    ) * NPTS + gc0 + 1] = make_float2(g01r, g01i);
    gp[(gr0 + 1) * NPTS + gc0    ] = make_float2(g10r, g10i);
    gp[(gr0 + 1) * NPTS + gc0 + 1] = make_float2(g11r, g11i);
}

// ---------------------------------------------------------------------------
// Kernel C: sum K-partials, form K = |G|^2, reduce polarity & sum(K^2).
// ---------------------------------------------------------------------------
__global__ __launch_bounds__(256)
void reduce_kernel(const float2* __restrict__ Gpart,
                   const float* __restrict__ labels,
                   double* __restrict__ acc)
{
    const int idx = blockIdx.x * 256 + threadIdx.x;   // 0..16383
    float gr = 0.f, gi = 0.f;
    #pragma unroll
    for (int p = 0; p < KSPLIT; ++p) {
        const float2 g = Gpart[p * (NPTS * NPTS) + idx];
        gr += g.x; gi += g.y;
    }
    const int i  = idx >> 7;
    const int jj = idx & (NPTS - 1);
    const float K = gr * gr + gi * gi;
    double pol = (double)(labels[i] * labels[jj]) * (double)K;
    double k2  = (double)K * (double)K;
    #pragma unroll
    for (int off = 32; off > 0; off >>= 1) {
        pol += __shfl_xor(pol, off, 64);
        k2  += __shfl_xor(k2,  off, 64);
    }
    __shared__ double sp[4], sk[4];
    const int wv = threadIdx.x >> 6;
    if ((threadIdx.x & 63) == 0) { sp[wv] = pol; sk[wv] = k2; }
    __syncthreads();
    if (threadIdx.x == 0) {
        atomicAdd(&acc[0], sp[0] + sp[1] + sp[2] + sp[3]);
        atomicAdd(&acc[1], sk[0] + sk[1] + sk[2] + sk[3]);
    }
}

__global__ void finalize_kernel(const double* __restrict__ acc,
                                const float* __restrict__ labels,
                                float* __restrict__ out)
{
    double sumL2 = 0.0;
    for (int i = 0; i < NPTS; ++i) {
        const double l = (double)labels[i];
        sumL2 += l * l;
    }
    out[0] = (float)(acc[0] / (sumL2 * sqrt(acc[1])));
}

// ---------------------------------------------------------------------------
extern "C" void kernel_launch(void* const* d_in, const int* in_sizes, int n_in,
                              void* d_out, int out_size, void* d_ws, size_t ws_size,
                              hipStream_t stream)
{
    const float* data   = (const float*)d_in[0];   // [128,100]
    const float* labels = (const float*)d_in[1];   // [128]
    const float* params = (const float*)d_in[2];   // [10,2,10]
    float* out = (float*)d_out;

    float2* psi   = (float2*)d_ws;                                   // 1 MiB
    float2* Gpart = (float2*)((char*)d_ws + (size_t)(1u << 20));     // 2 MiB
    double* acc   = (double*)((char*)d_ws + (size_t)(3u << 20));     // 16 B

    states_kernel<<<NPTS, 256, 0, stream>>>(data, params, psi, acc);
    gram_kernel<<<TS ? 256 : 0, 256, 0, stream>>>(psi, Gpart);
    reduce_kernel<<<(NPTS * NPTS) / 256, 256, 0, stream>>>(Gpart, labels, acc);
    finalize_kernel<<<1, 1, 0, stream>>>(acc, labels, out);
}